// Round 2
// baseline (287.475 us; speedup 1.0000x reference)
//
#include <hip/hip_runtime.h>

#define D_NODE 256
#define D_EDGE 128
#define D_HEAD 32
#define NN 512

typedef float f4v __attribute__((ext_vector_type(4)));

// ---------------------------------------------------------------------------
// Kernel 1: LayerNorm(node) -> x; left = x@w_left + b_left (natural layout);
//           right = x@w_right + b_right. One block per row n, 256 threads.
// ---------------------------------------------------------------------------
__global__ __launch_bounds__(256) void ln_proj_kernel(
    const float* __restrict__ node, const float* __restrict__ ln_w,
    const float* __restrict__ ln_b, const float* __restrict__ w_left,
    const float* __restrict__ b_left, const float* __restrict__ w_right,
    const float* __restrict__ b_right, float* __restrict__ left,
    float* __restrict__ right) {
  __shared__ float xs[D_NODE];
  __shared__ float red[10];
  __shared__ float part[4][64];
  const int n = blockIdx.x;
  const int t = threadIdx.x;
  float v = node[n * D_NODE + t];
  float s = v, ss = v * v;
#pragma unroll
  for (int o = 32; o > 0; o >>= 1) {
    s += __shfl_down(s, o);
    ss += __shfl_down(ss, o);
  }
  if ((t & 63) == 0) {
    red[t >> 6] = s;
    red[4 + (t >> 6)] = ss;
  }
  __syncthreads();
  if (t == 0) {
    float S = red[0] + red[1] + red[2] + red[3];
    float SS = red[4] + red[5] + red[6] + red[7];
    float mu = S * (1.0f / D_NODE);
    float var = SS * (1.0f / D_NODE) - mu * mu;
    red[8] = mu;
    red[9] = rsqrtf(var + 1e-5f);
  }
  __syncthreads();
  const float mu = red[8], rs = red[9];
  xs[t] = (v - mu) * rs * ln_w[t] + ln_b[t];
  __syncthreads();
  {
    const int col = t & 63;
    const int q = t >> 6;
    const int c = col & 31;
    const float* w = (col < 32) ? w_left : w_right;
    float acc = 0.f;
    const int d0 = q * 64;
#pragma unroll 8
    for (int d = d0; d < d0 + 64; ++d) acc = fmaf(xs[d], w[d * D_HEAD + c], acc);
    part[q][col] = acc;
  }
  __syncthreads();
  if (t < 64) {
    const int c = t & 31;
    const bool isL = (t < 32);
    float acc = part[0][t] + part[1][t] + part[2][t] + part[3][t] +
                (isL ? b_left[c] : b_right[c]);
    (isL ? left : right)[n * D_HEAD + c] = acc;
  }
}

// ---------------------------------------------------------------------------
// Kernel 2: tmp[m,i,e] = sum_j right[m,j] * w_out[(i*32+j)*128 + e]
// Block covers 4 m's and 8 i's -> each w_out line reused 4x in registers.
// Grid (128, 4), 256 threads: e4 = t&31 (float4 over e), i = i0 + (t>>5).
// ---------------------------------------------------------------------------
__global__ __launch_bounds__(256) void rw_kernel(
    const float* __restrict__ right, const float* __restrict__ w_out,
    float* __restrict__ tmp) {
  const int m0 = blockIdx.x * 4;
  const int i = blockIdx.y * 8 + (threadIdx.x >> 5);
  const int e4 = threadIdx.x & 31;
  const float4* wp = (const float4*)(w_out + i * D_HEAD * D_EDGE) + e4;
  const float* r = right + m0 * D_HEAD;  // wave-uniform -> s_load
  float4 a0 = {0, 0, 0, 0}, a1 = {0, 0, 0, 0}, a2 = {0, 0, 0, 0},
         a3 = {0, 0, 0, 0};
#pragma unroll
  for (int j = 0; j < D_HEAD; ++j) {
    const float4 w4 = wp[j * (D_EDGE / 4)];
    const float r0 = r[j], r1 = r[32 + j], r2 = r[64 + j], r3 = r[96 + j];
    a0.x = fmaf(r0, w4.x, a0.x); a0.y = fmaf(r0, w4.y, a0.y);
    a0.z = fmaf(r0, w4.z, a0.z); a0.w = fmaf(r0, w4.w, a0.w);
    a1.x = fmaf(r1, w4.x, a1.x); a1.y = fmaf(r1, w4.y, a1.y);
    a1.z = fmaf(r1, w4.z, a1.z); a1.w = fmaf(r1, w4.w, a1.w);
    a2.x = fmaf(r2, w4.x, a2.x); a2.y = fmaf(r2, w4.y, a2.y);
    a2.z = fmaf(r2, w4.z, a2.z); a2.w = fmaf(r2, w4.w, a2.w);
    a3.x = fmaf(r3, w4.x, a3.x); a3.y = fmaf(r3, w4.y, a3.y);
    a3.z = fmaf(r3, w4.z, a3.z); a3.w = fmaf(r3, w4.w, a3.w);
  }
  ((float4*)(tmp + ((m0 + 0) * D_HEAD + i) * D_EDGE))[e4] = a0;
  ((float4*)(tmp + ((m0 + 1) * D_HEAD + i) * D_EDGE))[e4] = a1;
  ((float4*)(tmp + ((m0 + 2) * D_HEAD + i) * D_EDGE))[e4] = a2;
  ((float4*)(tmp + ((m0 + 3) * D_HEAD + i) * D_EDGE))[e4] = a3;
}

// ---------------------------------------------------------------------------
// Kernel 3 (workhorse, streaming): out[n,m,e] = b_out[e] + edge[n,m,e]
//                                + sum_i left[n,i] * tmp[m,i,e]
// REDESIGN vs round 0: no LDS, no barriers, 4x the blocks.
//  - Block = one m-PAIR x 32 n-rows (grid 4096, 256 thr); each wave owns one
//    8-row group. Round-0 version: 1024 blocks = 4 blocks/CU hard cap, 32 KB
//    LDS -> 5 blocks/CU cap, measured OccupancyPercent 29, hbm 2.5 TB/s.
//  - tmp slice (16 KB per m) read directly through L1/L2 as float4: one 16 B
//    load feeds 8 rows x 4 lanes of FMA. Total tmp L2 traffic ~512 MB, ~15 us
//    of the 34.5 TB/s L2 - cheap vs the HBM stream it unblocks.
//  - edge folded into acc at init (no eb[] double buffer) -> VGPR <= 64 so the
//    occupancy band stays 8 waves/SIMD (32 waves/CU, 16-block queue per CU).
//  - XCD-chunked swizzle: bid&7 = XCD (round-robin dispatch heuristic); each
//    XCD owns m-pairs [x*32, x*32+32) -> tmp working set 1 MB/XCD, L2-resident.
// Lane: mh = lane>>5 (which m of pair), e4 = lane&31 (float4 over e);
// per wave-instruction edge/out access stays 1 KB contiguous.
// ---------------------------------------------------------------------------
__global__ __launch_bounds__(256) void fuse_kernel(
    const float* __restrict__ left, const float* __restrict__ tmp,
    const float* __restrict__ b_out, const float* __restrict__ edge,
    float* __restrict__ out) {
  const int bid = blockIdx.x;
  const int xcd = bid & 7;
  const int rr = bid >> 3;               // [0, 512)
  const int p = (xcd << 5) | (rr & 31);  // m-pair id [0, 256)
  const int chunk = rr >> 5;             // n-chunk id [0, 16)
  const int m0 = p * 2;
  const int t = threadIdx.x;
  const int lane = t & 63;
  const int wv = t >> 6;
  const int e4 = lane & 31;
  const int mh = lane >> 5;
  const int n0 = chunk * 32 + wv * 8;

  const float4 be = ((const float4*)b_out)[e4];
  const float4* tp = (const float4*)(tmp + (m0 + mh) * (D_HEAD * D_EDGE)) + e4;
  const float4* edge4 = (const float4*)edge;
  float4* out4 = (float4*)out;
  const int rowstr = NN * (D_EDGE / 4);  // float4 stride n -> n+1
  const int base = (n0 * NN + m0) * (D_EDGE / 4) + lane;

  float4 acc[8];
#pragma unroll
  for (int q = 0; q < 8; ++q) {
    const float4 ev = edge4[base + q * rowstr];
    acc[q].x = be.x + ev.x;
    acc[q].y = be.y + ev.y;
    acc[q].z = be.z + ev.z;
    acc[q].w = be.w + ev.w;
  }
  const float* lp = left + n0 * D_HEAD;  // wave-uniform -> s_load
#pragma unroll 4
  for (int i = 0; i < D_HEAD; ++i) {
    const float4 tv = tp[i * (D_EDGE / 4)];
#pragma unroll
    for (int q = 0; q < 8; ++q) {
      const float l = lp[q * D_HEAD + i];
      acc[q].x = fmaf(l, tv.x, acc[q].x);
      acc[q].y = fmaf(l, tv.y, acc[q].y);
      acc[q].z = fmaf(l, tv.z, acc[q].z);
      acc[q].w = fmaf(l, tv.w, acc[q].w);
    }
  }
#pragma unroll
  for (int q = 0; q < 8; ++q)
    __builtin_nontemporal_store(*(const f4v*)&acc[q],
                                (f4v*)(out4 + base + q * rowstr));
}

extern "C" void kernel_launch(void* const* d_in, const int* in_sizes, int n_in,
                              void* d_out, int out_size, void* d_ws, size_t ws_size,
                              hipStream_t stream) {
  const float* node    = (const float*)d_in[0];
  const float* edge    = (const float*)d_in[1];
  const float* ln_w    = (const float*)d_in[2];
  const float* ln_b    = (const float*)d_in[3];
  const float* w_left  = (const float*)d_in[4];
  const float* b_left  = (const float*)d_in[5];
  const float* w_right = (const float*)d_in[6];
  const float* b_right = (const float*)d_in[7];
  const float* w_out   = (const float*)d_in[8];
  const float* b_out   = (const float*)d_in[9];
  float* out = (float*)d_out;

  float* left  = (float*)d_ws;                 // [512][32]
  float* right = left + NN * D_HEAD;           // [512][32]
  float* tmp   = right + NN * D_HEAD;          // [512][32][128] (8 MB)

  ln_proj_kernel<<<NN, 256, 0, stream>>>(node, ln_w, ln_b, w_left, b_left,
                                         w_right, b_right, left, right);
  rw_kernel<<<dim3(NN / 4, 4), 256, 0, stream>>>(right, w_out, tmp);
  fuse_kernel<<<dim3(NN * 8), 256, 0, stream>>>(left, tmp, b_out, edge, out);
}

// Round 3
// 269.808 us; speedup vs baseline: 1.0655x; 1.0655x over previous
//
#include <hip/hip_runtime.h>

#define D_NODE 256
#define D_EDGE 128
#define D_HEAD 32
#define NN 512

typedef float f4v __attribute__((ext_vector_type(4)));

// ---------------------------------------------------------------------------
// Kernel 1: LayerNorm(node) -> x; left = x@w_left + b_left (natural layout);
//           right = x@w_right + b_right. One block per row n, 256 threads.
// ---------------------------------------------------------------------------
__global__ __launch_bounds__(256) void ln_proj_kernel(
    const float* __restrict__ node, const float* __restrict__ ln_w,
    const float* __restrict__ ln_b, const float* __restrict__ w_left,
    const float* __restrict__ b_left, const float* __restrict__ w_right,
    const float* __restrict__ b_right, float* __restrict__ left,
    float* __restrict__ right) {
  __shared__ float xs[D_NODE];
  __shared__ float red[10];
  __shared__ float part[4][64];
  const int n = blockIdx.x;
  const int t = threadIdx.x;
  float v = node[n * D_NODE + t];
  float s = v, ss = v * v;
#pragma unroll
  for (int o = 32; o > 0; o >>= 1) {
    s += __shfl_down(s, o);
    ss += __shfl_down(ss, o);
  }
  if ((t & 63) == 0) {
    red[t >> 6] = s;
    red[4 + (t >> 6)] = ss;
  }
  __syncthreads();
  if (t == 0) {
    float S = red[0] + red[1] + red[2] + red[3];
    float SS = red[4] + red[5] + red[6] + red[7];
    float mu = S * (1.0f / D_NODE);
    float var = SS * (1.0f / D_NODE) - mu * mu;
    red[8] = mu;
    red[9] = rsqrtf(var + 1e-5f);
  }
  __syncthreads();
  const float mu = red[8], rs = red[9];
  xs[t] = (v - mu) * rs * ln_w[t] + ln_b[t];
  __syncthreads();
  {
    const int col = t & 63;
    const int q = t >> 6;
    const int c = col & 31;
    const float* w = (col < 32) ? w_left : w_right;
    float acc = 0.f;
    const int d0 = q * 64;
#pragma unroll 8
    for (int d = d0; d < d0 + 64; ++d) acc = fmaf(xs[d], w[d * D_HEAD + c], acc);
    part[q][col] = acc;
  }
  __syncthreads();
  if (t < 64) {
    const int c = t & 31;
    const bool isL = (t < 32);
    float acc = part[0][t] + part[1][t] + part[2][t] + part[3][t] +
                (isL ? b_left[c] : b_right[c]);
    (isL ? left : right)[n * D_HEAD + c] = acc;
  }
}

// ---------------------------------------------------------------------------
// Kernel 2: tmp[m,i,e] = sum_j right[m,j] * w_out[(i*32+j)*128 + e]
// Block covers 4 m's and 8 i's -> each w_out line reused 4x in registers.
// Grid (128, 4), 256 threads: e4 = t&31 (float4 over e), i = i0 + (t>>5).
// ---------------------------------------------------------------------------
__global__ __launch_bounds__(256) void rw_kernel(
    const float* __restrict__ right, const float* __restrict__ w_out,
    float* __restrict__ tmp) {
  const int m0 = blockIdx.x * 4;
  const int i = blockIdx.y * 8 + (threadIdx.x >> 5);
  const int e4 = threadIdx.x & 31;
  const float4* wp = (const float4*)(w_out + i * D_HEAD * D_EDGE) + e4;
  const float* r = right + m0 * D_HEAD;  // wave-uniform -> s_load
  float4 a0 = {0, 0, 0, 0}, a1 = {0, 0, 0, 0}, a2 = {0, 0, 0, 0},
         a3 = {0, 0, 0, 0};
#pragma unroll
  for (int j = 0; j < D_HEAD; ++j) {
    const float4 w4 = wp[j * (D_EDGE / 4)];
    const float r0 = r[j], r1 = r[32 + j], r2 = r[64 + j], r3 = r[96 + j];
    a0.x = fmaf(r0, w4.x, a0.x); a0.y = fmaf(r0, w4.y, a0.y);
    a0.z = fmaf(r0, w4.z, a0.z); a0.w = fmaf(r0, w4.w, a0.w);
    a1.x = fmaf(r1, w4.x, a1.x); a1.y = fmaf(r1, w4.y, a1.y);
    a1.z = fmaf(r1, w4.z, a1.z); a1.w = fmaf(r1, w4.w, a1.w);
    a2.x = fmaf(r2, w4.x, a2.x); a2.y = fmaf(r2, w4.y, a2.y);
    a2.z = fmaf(r2, w4.z, a2.z); a2.w = fmaf(r2, w4.w, a2.w);
    a3.x = fmaf(r3, w4.x, a3.x); a3.y = fmaf(r3, w4.y, a3.y);
    a3.z = fmaf(r3, w4.z, a3.z); a3.w = fmaf(r3, w4.w, a3.w);
  }
  ((float4*)(tmp + ((m0 + 0) * D_HEAD + i) * D_EDGE))[e4] = a0;
  ((float4*)(tmp + ((m0 + 1) * D_HEAD + i) * D_EDGE))[e4] = a1;
  ((float4*)(tmp + ((m0 + 2) * D_HEAD + i) * D_EDGE))[e4] = a2;
  ((float4*)(tmp + ((m0 + 3) * D_HEAD + i) * D_EDGE))[e4] = a3;
}

// ---------------------------------------------------------------------------
// Kernel 3 (workhorse, streaming): out[n,m,e] = b_out[e] + edge[n,m,e]
//                                + sum_i left[n,i] * tmp[m,i,e]
// Round-3: round-0's proven inner structure (LDS tmp pair, eb[] rolling edge
// prefetch, edge added AFTER the FMA loop) with the occupancy cap removed:
//  - n-chunk halved 128 -> 64 (2 groups of 8 rows per wave), grid 1024 -> 2048.
//    LDS 32 KB caps residency at 5 blocks/CU = 20 waves/CU (62.5%) with an
//    8-deep block queue per CU (round 0: exactly 4 resident, no queue, 29%).
//  - VGPR stays 64: rolling eb keeps one 8-row group in flight + acc (32+32).
//  - Round-2 post-mortem: folding edge into acc INIT made the whole FMA chain
//    depend on the edge loads (occupancy 54% but dur 102us, hbm 2.0 TB/s).
//    Edge must be consumed at the END so its latency hides under the i-loop.
//  - Free XCD locality: linear block id mod 8 = m-pair mod 8, so all 8
//    n-chunks of an m-pair land on one XCD -> tmp ~1 MB/XCD, L2-resident.
// Lane: mh = lane>>5 (which m of pair), e4 = lane&31 (float4 over e).
// ---------------------------------------------------------------------------
__global__ __launch_bounds__(256) void fuse_kernel(
    const float* __restrict__ left, const float* __restrict__ tmp,
    const float* __restrict__ b_out, const float* __restrict__ edge,
    float* __restrict__ out) {
  __shared__ float tl[2 * D_HEAD * D_EDGE];  // 32 KB
  const int m0 = blockIdx.x * 2;
  const int t = threadIdx.x;
  {  // stage tmp[m0] and tmp[m0+1] (contiguous 8192 floats)
    const float4* ts = (const float4*)(tmp + m0 * D_HEAD * D_EDGE);
    float4* td = (float4*)tl;
#pragma unroll
    for (int k = 0; k < 8; ++k) td[t + 256 * k] = ts[t + 256 * k];
  }
  const int lane = t & 63;
  const int wv = __builtin_amdgcn_readfirstlane(t >> 6);
  const int e4 = lane & 31;
  const int mh = lane >> 5;
  const int n0 = blockIdx.y * 64 + wv * 16;
  const float4 be = ((const float4*)b_out)[e4];
  const float* tb = tl + mh * (D_HEAD * D_EDGE) + e4 * 4;
  const float4* edge4 = (const float4*)edge;
  float4* out4 = (float4*)out;
  const int rowstr = NN * (D_EDGE / 4);  // float4 stride for n -> n+1
  const int base = (n0 * NN + m0) * (D_EDGE / 4) + lane;

  float4 eb[2][8];
#pragma unroll
  for (int r = 0; r < 8; ++r) eb[0][r] = edge4[base + r * rowstr];
  __syncthreads();

#pragma unroll
  for (int g = 0; g < 2; ++g) {
    const int cur = g & 1;
    const int gb = base + g * 8 * rowstr;
    if (g < 1) {  // prefetch next group's edge rows
#pragma unroll
      for (int r = 0; r < 8; ++r)
        eb[cur ^ 1][r] = edge4[gb + (8 + r) * rowstr];
    }
    float4 acc[8];
#pragma unroll
    for (int r = 0; r < 8; ++r) acc[r] = be;
    const float* lp = left + (n0 + g * 8) * D_HEAD;  // uniform -> s_load
#pragma unroll 4
    for (int i = 0; i < D_HEAD; ++i) {
      const float4 tv = *(const float4*)(tb + i * D_EDGE);
#pragma unroll
      for (int r = 0; r < 8; ++r) {
        const float l = lp[r * D_HEAD + i];
        acc[r].x = fmaf(l, tv.x, acc[r].x);
        acc[r].y = fmaf(l, tv.y, acc[r].y);
        acc[r].z = fmaf(l, tv.z, acc[r].z);
        acc[r].w = fmaf(l, tv.w, acc[r].w);
      }
    }
#pragma unroll
    for (int r = 0; r < 8; ++r) {
      acc[r].x += eb[cur][r].x;
      acc[r].y += eb[cur][r].y;
      acc[r].z += eb[cur][r].z;
      acc[r].w += eb[cur][r].w;
      __builtin_nontemporal_store(*(const f4v*)&acc[r],
                                  (f4v*)(out4 + gb + r * rowstr));
    }
  }
}

extern "C" void kernel_launch(void* const* d_in, const int* in_sizes, int n_in,
                              void* d_out, int out_size, void* d_ws, size_t ws_size,
                              hipStream_t stream) {
  const float* node    = (const float*)d_in[0];
  const float* edge    = (const float*)d_in[1];
  const float* ln_w    = (const float*)d_in[2];
  const float* ln_b    = (const float*)d_in[3];
  const float* w_left  = (const float*)d_in[4];
  const float* b_left  = (const float*)d_in[5];
  const float* w_right = (const float*)d_in[6];
  const float* b_right = (const float*)d_in[7];
  const float* w_out   = (const float*)d_in[8];
  const float* b_out   = (const float*)d_in[9];
  float* out = (float*)d_out;

  float* left  = (float*)d_ws;                 // [512][32]
  float* right = left + NN * D_HEAD;           // [512][32]
  float* tmp   = right + NN * D_HEAD;          // [512][32][128] (8 MB)

  ln_proj_kernel<<<NN, 256, 0, stream>>>(node, ln_w, ln_b, w_left, b_left,
                                         w_right, b_right, left, right);
  rw_kernel<<<dim3(NN / 4, 4), 256, 0, stream>>>(right, w_out, tmp);
  fuse_kernel<<<dim3(NN / 2, 8), 256, 0, stream>>>(left, tmp, b_out, edge, out);
}